// Round 1
// baseline (272.391 us; speedup 1.0000x reference)
//
#include <hip/hip_runtime.h>
#include <math.h>

// LinearAttend: B=4, N=8, D=64, S=8192, fp32.
// out[b,n,j,s] = sum_i context[i,j] * qs[i,s]
//   context[i,j] = sum_s softmax_s(k)[i,s] * v[j,s]
//   qs = softmax_d(q) * D^-0.5
// No fp32 MFMA on CDNA4 -> vector-ALU GEMMs with conflict-free LDS tiling.

constexpr int BHEADS = 32;   // B*N
constexpr int DH     = 64;   // dim_head
constexpr int SEQ    = 8192; // seq len
constexpr float QSCALE = 0.125f; // 1/sqrt(64)

// ---------------------------------------------------------------------------
// Kernel A: ctx_raw[head][i][j] = sum_s exp(k[i,s]) * v[j,s]
//           Z[head][i]          = sum_s exp(k[i,s])
// grid: (32 seq-chunks of 256, 32 heads), block 256.
// LDS layout: transposed [s][i] with XOR swizzle on 16B chunks so that
//   - GEMM e-reads broadcast across 16 lanes (free)
//   - GEMM v-reads hit all 16 chunk positions (2-way, free per m136)
//   - staging b128 writes spread over all 8 bank groups (optimal)
// ---------------------------------------------------------------------------
__global__ __launch_bounds__(256)
void ctx_kernel(const float* __restrict__ K, const float* __restrict__ V,
                float* __restrict__ ctx, float* __restrict__ Z)
{
    const int head  = blockIdx.y;
    const int chunk = blockIdx.x;          // 32 chunks x 256 seq
    const int t     = threadIdx.x;

    const float* kh = K + (size_t)head * DH * SEQ;
    const float* vh = V + (size_t)head * DH * SEQ;

    __shared__ __align__(16) float et[64 * 64];  // [s][i] swizzled, exp(k)
    __shared__ __align__(16) float vt[64 * 64];  // [s][j] swizzled

    const int ti  = t >> 4;   // 0..15 -> i0 = 4*ti
    const int tj  = t & 15;   // 0..15 -> j0 = 4*tj
    const int s_l = t & 63;   // staging: seq lane
    const int g   = t >> 6;   // staging: i-chunk group 0..3

    float acc[4][4];
    #pragma unroll
    for (int a = 0; a < 4; ++a)
        #pragma unroll
        for (int b = 0; b < 4; ++b) acc[a][b] = 0.0f;
    float zacc[4] = {0.f, 0.f, 0.f, 0.f};

    for (int st = 0; st < 4; ++st) {
        const int s_base = chunk * 256 + st * 64;
        // ---- stage 64x64 k (exp'd) and v tiles, transposed, swizzled ----
        #pragma unroll
        for (int p = 0; p < 4; ++p) {
            const int c  = g + 4 * p;      // i-chunk index 0..15
            const int i0 = 4 * c;
            const size_t col = (size_t)s_base + s_l;
            float4 e4, v4;
            e4.x = __expf(kh[(size_t)(i0 + 0) * SEQ + col]);
            e4.y = __expf(kh[(size_t)(i0 + 1) * SEQ + col]);
            e4.z = __expf(kh[(size_t)(i0 + 2) * SEQ + col]);
            e4.w = __expf(kh[(size_t)(i0 + 3) * SEQ + col]);
            v4.x = vh[(size_t)(i0 + 0) * SEQ + col];
            v4.y = vh[(size_t)(i0 + 1) * SEQ + col];
            v4.z = vh[(size_t)(i0 + 2) * SEQ + col];
            v4.w = vh[(size_t)(i0 + 3) * SEQ + col];
            const int pos = c ^ (s_l & 15);          // XOR swizzle
            ((float4*)(et + s_l * 64))[pos] = e4;
            ((float4*)(vt + s_l * 64))[pos] = v4;
        }
        __syncthreads();
        // ---- 4x4 register-tile outer product over 64 s ----
        #pragma unroll 4
        for (int s = 0; s < 64; ++s) {
            const float4 e4 = ((const float4*)(et + s * 64))[ti ^ (s & 15)];
            const float4 v4 = ((const float4*)(vt + s * 64))[tj ^ (s & 15)];
            const float ee[4] = {e4.x, e4.y, e4.z, e4.w};
            const float vv[4] = {v4.x, v4.y, v4.z, v4.w};
            #pragma unroll
            for (int a = 0; a < 4; ++a) {
                #pragma unroll
                for (int b = 0; b < 4; ++b)
                    acc[a][b] = fmaf(ee[a], vv[b], acc[a][b]);
            }
            zacc[0] += ee[0]; zacc[1] += ee[1];
            zacc[2] += ee[2]; zacc[3] += ee[3];
        }
        __syncthreads();
    }

    float* ch = ctx + head * DH * DH;
    #pragma unroll
    for (int a = 0; a < 4; ++a)
        #pragma unroll
        for (int b = 0; b < 4; ++b)
            unsafeAtomicAdd(&ch[(4 * ti + a) * DH + 4 * tj + b], acc[a][b]);
    if (tj == 0) {  // zacc depends only on ti -> one lane per row set
        #pragma unroll
        for (int a = 0; a < 4; ++a)
            unsafeAtomicAdd(&Z[head * DH + 4 * ti + a], zacc[a]);
    }
}

// ---------------------------------------------------------------------------
// Kernel B: out[head][j][s] = (scale / W_s) * sum_i (ctx[i][j]/Z_i) * exp(q[i,s])
// grid: (64 s-tiles of 128, 32 heads), block 256.
// eq kept in natural [i][s] layout: reduction dim i is the LDS row ->
// b128 reads along j/s are conflict-free (2-way max).
// ---------------------------------------------------------------------------
__global__ __launch_bounds__(256)
void out_kernel(const float* __restrict__ Q, const float* __restrict__ ctx,
                const float* __restrict__ Z, float* __restrict__ out)
{
    const int head  = blockIdx.y;
    const int stile = blockIdx.x;          // 64 tiles x 128 seq
    const int t     = threadIdx.x;
    const int s0    = stile * 128;

    __shared__ __align__(16) float eq[64 * 128];  // exp(q), [i][s]
    __shared__ __align__(16) float cs[64 * 64];   // ctx[i][j] / Z_i
    __shared__ float rz[64];
    __shared__ float wpart[2][128];
    __shared__ __align__(16) float wsh[128];      // scale / W_s

    const float* qh = Q + (size_t)head * DH * SEQ + s0;

    if (t < 64) rz[t] = 1.0f / Z[head * DH + t];

    // ---- stage exp(q) tile 64 x 128 ----
    {
        const int i  = t >> 4;     // 0..15
        const int sg = t & 15;
        #pragma unroll
        for (int p = 0; p < 4; ++p) {
            const int row = i + 16 * p;
            #pragma unroll
            for (int h = 0; h < 2; ++h) {
                const int col = 4 * sg + 64 * h;
                float4 qv = *(const float4*)(qh + (size_t)row * SEQ + col);
                float4 ev;
                ev.x = __expf(qv.x); ev.y = __expf(qv.y);
                ev.z = __expf(qv.z); ev.w = __expf(qv.w);
                *(float4*)(eq + row * 128 + col) = ev;
            }
        }
    }
    __syncthreads();

    // ---- stage cs = ctx * (1/Z_i)  (ctx is L2-resident, 16 KiB/head) ----
    {
        const int i  = t >> 2;     // 0..63
        const int jg = t & 3;
        const float* ch = ctx + head * DH * DH;
        const float r = rz[i];
        #pragma unroll
        for (int p = 0; p < 4; ++p) {
            const int j0 = 4 * (jg + 4 * p);
            float4 cv = *(const float4*)(ch + i * DH + j0);
            cv.x *= r; cv.y *= r; cv.z *= r; cv.w *= r;
            *(float4*)(cs + i * DH + j0) = cv;
        }
    }
    // ---- column sums W_s over i (two half-reductions) ----
    {
        const int s = t & 127;
        const int h = t >> 7;
        float w = 0.0f;
        #pragma unroll 8
        for (int i = 32 * h; i < 32 * h + 32; ++i) w += eq[i * 128 + s];
        wpart[h][s] = w;
    }
    __syncthreads();
    if (t < 128) wsh[t] = QSCALE / (wpart[0][t] + wpart[1][t]);
    __syncthreads();

    // ---- GEMM: 4j x (4s + 4s) register tile, K = 64 over i ----
    const int tj = t >> 4;    // j0 = 4*tj
    const int ts = t & 15;    // s cols {4*ts..} and {64+4*ts..}
    float acca[4][4], accb[4][4];
    #pragma unroll
    for (int a = 0; a < 4; ++a)
        #pragma unroll
        for (int b = 0; b < 4; ++b) { acca[a][b] = 0.f; accb[a][b] = 0.f; }

    #pragma unroll 4
    for (int i = 0; i < 64; ++i) {
        const float4 c4 = *(const float4*)(cs + i * DH + 4 * tj);       // broadcast
        const float4 a4 = *(const float4*)(eq + i * 128 + 4 * ts);      // 2-way
        const float4 b4 = *(const float4*)(eq + i * 128 + 64 + 4 * ts); // 2-way
        const float cc[4] = {c4.x, c4.y, c4.z, c4.w};
        const float aa[4] = {a4.x, a4.y, a4.z, a4.w};
        const float bb[4] = {b4.x, b4.y, b4.z, b4.w};
        #pragma unroll
        for (int j = 0; j < 4; ++j) {
            #pragma unroll
            for (int x = 0; x < 4; ++x) {
                acca[j][x] = fmaf(cc[j], aa[x], acca[j][x]);
                accb[j][x] = fmaf(cc[j], bb[x], accb[j][x]);
            }
        }
    }

    // ---- epilogue: scale by per-column softmax denom, coalesced f4 stores ----
    const float4 wa = *(const float4*)(wsh + 4 * ts);
    const float4 wb = *(const float4*)(wsh + 64 + 4 * ts);
    float* oh = out + (size_t)head * DH * SEQ + s0;
    #pragma unroll
    for (int j = 0; j < 4; ++j) {
        const int row = 4 * tj + j;
        float4 o1, o2;
        o1.x = acca[j][0] * wa.x; o1.y = acca[j][1] * wa.y;
        o1.z = acca[j][2] * wa.z; o1.w = acca[j][3] * wa.w;
        o2.x = accb[j][0] * wb.x; o2.y = accb[j][1] * wb.y;
        o2.z = accb[j][2] * wb.z; o2.w = accb[j][3] * wb.w;
        *(float4*)(oh + (size_t)row * SEQ + 4 * ts) = o1;
        *(float4*)(oh + (size_t)row * SEQ + 64 + 4 * ts) = o2;
    }
}

extern "C" void kernel_launch(void* const* d_in, const int* in_sizes, int n_in,
                              void* d_out, int out_size, void* d_ws, size_t ws_size,
                              hipStream_t stream)
{
    const float* q = (const float*)d_in[0];
    const float* k = (const float*)d_in[1];
    const float* v = (const float*)d_in[2];
    float* out = (float*)d_out;

    float* ctx = (float*)d_ws;                       // 32*64*64 fp32 = 512 KiB
    float* Z   = ctx + BHEADS * DH * DH;             // 32*64 fp32   =   8 KiB

    const size_t zero_bytes = (size_t)(BHEADS * DH * DH + BHEADS * DH) * sizeof(float);
    hipMemsetAsync(d_ws, 0, zero_bytes, stream);

    ctx_kernel<<<dim3(32, BHEADS), 256, 0, stream>>>(k, v, ctx, Z);
    out_kernel<<<dim3(64, BHEADS), 256, 0, stream>>>(q, ctx, Z, out);
}

// Round 2
// 238.098 us; speedup vs baseline: 1.1440x; 1.1440x over previous
//
#include <hip/hip_runtime.h>
#include <math.h>

// LinearAttend: B=4, N=8, D=64, S=8192, fp32 in/out.
// out[j,s] = (1/W_s)*scale * sum_i (ctx[i,j]/Z_i) * exp(q[i,s])
//   ctx[i,j] = sum_s exp(k[i,s]) * v[j,s],  Z_i = sum_s exp(k[i,s])
// Both GEMMs on fp16 MFMA (16x16x32, fp32 accum); exp/softmax denominators fp32.

typedef _Float16 half8 __attribute__((ext_vector_type(8)));
typedef _Float16 half4v __attribute__((ext_vector_type(4)));
typedef float floatx4 __attribute__((ext_vector_type(4)));

constexpr int BHEADS = 32;
constexpr int DH     = 64;
constexpr int SEQ    = 8192;
constexpr float QSCALE = 0.125f;   // 64^-0.5

// ---------------------------------------------------------------------------
// Kernel A: ctx[i][j] += sum_s e[i,s]*v[j,s]; Z[i] += sum_s e[i,s]
// grid (32 chunks x 32 heads), 256 thr. 4 s-tiles of 64 per block.
// LDS [i][s] fp16, stride 72 halves (144 B = 9*16B: b128-aligned rows, 2-way
// banks = free). MFMA 16x16x32_f16: wave w owns i-strip 16w..16w+15.
// ---------------------------------------------------------------------------
__global__ __launch_bounds__(256)
void ctx_kernel(const float* __restrict__ K, const float* __restrict__ V,
                float* __restrict__ ctx, float* __restrict__ Z)
{
    const int head  = blockIdx.y;
    const int chunk = blockIdx.x;           // 32 chunks x 256 s
    const int t     = threadIdx.x;
    const int lane  = t & 63;
    const int w     = t >> 6;               // wave id 0..3
    const int ln    = lane & 15;
    const int q8    = lane >> 4;            // quad 0..3

    const float* kh = K + (size_t)head * DH * SEQ;
    const float* vh = V + (size_t)head * DH * SEQ;

    __shared__ __align__(16) _Float16 et[64 * 72];
    __shared__ __align__(16) _Float16 vt[64 * 72];
    __shared__ float zred[64 * 16];

    // staging map: thread t covers rows {r0+16p}, cols sc..sc+3 of a 64x64 tile
    const int r0 = t >> 4;
    const int sc = 4 * (t & 15);
    const int s_blk = chunk * 256;

    float4 pk[4], pv[4];
    #pragma unroll
    for (int p = 0; p < 4; ++p) {
        const size_t off = (size_t)(r0 + 16 * p) * SEQ + s_blk + sc;
        pk[p] = *(const float4*)(kh + off);
        pv[p] = *(const float4*)(vh + off);
    }

    floatx4 acc[4];
    #pragma unroll
    for (int jt = 0; jt < 4; ++jt) acc[jt] = (floatx4){0.f, 0.f, 0.f, 0.f};
    float zacc[4] = {0.f, 0.f, 0.f, 0.f};

    for (int ts = 0; ts < 4; ++ts) {
        // exp + cvt + LDS write (b64 stores)
        #pragma unroll
        for (int p = 0; p < 4; ++p) {
            const int i = r0 + 16 * p;
            const float e0 = __expf(pk[p].x), e1 = __expf(pk[p].y);
            const float e2 = __expf(pk[p].z), e3 = __expf(pk[p].w);
            zacc[p] += e0 + e1 + e2 + e3;
            *(half4v*)(et + i * 72 + sc) =
                (half4v){(_Float16)e0, (_Float16)e1, (_Float16)e2, (_Float16)e3};
            *(half4v*)(vt + i * 72 + sc) =
                (half4v){(_Float16)pv[p].x, (_Float16)pv[p].y,
                         (_Float16)pv[p].z, (_Float16)pv[p].w};
        }
        __syncthreads();
        // prefetch next tile while MFMA runs
        if (ts < 3) {
            #pragma unroll
            for (int p = 0; p < 4; ++p) {
                const size_t off = (size_t)(r0 + 16 * p) * SEQ + s_blk + (ts + 1) * 64 + sc;
                pk[p] = *(const float4*)(kh + off);
                pv[p] = *(const float4*)(vh + off);
            }
        }
        // MFMA: 2 K-steps of 32, wave strip i=16w.., all 4 j-tiles
        #pragma unroll
        for (int st = 0; st < 2; ++st) {
            const half8 a = *(const half8*)(et + (16 * w + ln) * 72 + st * 32 + q8 * 8);
            #pragma unroll
            for (int jt = 0; jt < 4; ++jt) {
                const half8 b = *(const half8*)(vt + (16 * jt + ln) * 72 + st * 32 + q8 * 8);
                acc[jt] = __builtin_amdgcn_mfma_f32_16x16x32_f16(a, b, acc[jt], 0, 0, 0);
            }
        }
        __syncthreads();
    }

    // merge partial ctx (split-K over chunks)
    float* ch = ctx + head * DH * DH;
    #pragma unroll
    for (int jt = 0; jt < 4; ++jt) {
        #pragma unroll
        for (int rr = 0; rr < 4; ++rr) {
            const int i = 16 * w + q8 * 4 + rr;   // C/D: row = quad*4 + reg
            const int j = 16 * jt + ln;           // C/D: col = lane&15
            unsafeAtomicAdd(&ch[i * DH + j], acc[jt][rr]);
        }
    }
    // Z reduction: [64 rows][16 col-partials]
    #pragma unroll
    for (int p = 0; p < 4; ++p) zred[(r0 + 16 * p) * 16 + (t & 15)] = zacc[p];
    __syncthreads();
    if (t < 64) {
        float z = 0.f;
        #pragma unroll
        for (int c = 0; c < 16; ++c) z += zred[t * 16 + c];
        unsafeAtomicAdd(&Z[head * DH + t], z);
    }
}

// ---------------------------------------------------------------------------
// Kernel B: out[j][s] = rw[s] * sum_i czT[j][i] * eq[i][s]
// grid (32 s-blocks x 32 heads), 256 thr, 4 rounds of 64 s.
// eq must be K(=i)-contiguous for MFMA frags -> two-step LDS transpose:
//   fp32 natural staging (stride 68) -> column reads -> exp -> half8 writes
//   into eqT[s][chunk^(s&7)] (XOR swizzle: uniform banks, conflict-free).
// W_s accumulated in fp32 during the transpose. czT staged once per block;
// A-frags persist in registers across rounds.
// ---------------------------------------------------------------------------
__global__ __launch_bounds__(256)
void out_kernel(const float* __restrict__ Q, const float* __restrict__ ctx,
                const float* __restrict__ Z, float* __restrict__ out)
{
    const int head = blockIdx.y;
    const int sb   = blockIdx.x;            // 32 x 256 s
    const int t    = threadIdx.x;
    const int lane = t & 63;
    const int w    = t >> 6;
    const int ln   = lane & 15;
    const int q8   = lane >> 4;

    __shared__ __align__(16) _Float16 czT[64 * 72];  // [j][i], stride 72
    __shared__ __align__(16) float    qf[64 * 68];   // [i][s] fp32, stride 68
    __shared__ __align__(16) _Float16 eqT[64 * 64];  // [s][i] fp16, swizzled chunks
    __shared__ float wred[64 * 4];
    __shared__ float rwsh[64];

    const float* qh = Q + (size_t)head * DH * SEQ;
    const int r0 = t >> 4;
    const int sc = 4 * (t & 15);
    const int s0 = sb * 256;

    // prefetch q round 0
    float4 pq[4];
    #pragma unroll
    for (int p = 0; p < 4; ++p)
        pq[p] = *(const float4*)(qh + (size_t)(r0 + 16 * p) * SEQ + s0 + sc);

    // stage czT[j][i] = ctx[i][j] / Z_i  (tiny, once per block)
    {
        const float* ch = ctx + head * DH * DH;
        #pragma unroll
        for (int p = 0; p < 4; ++p) {
            const int i = r0 + 16 * p;
            const float rz = 1.0f / Z[head * DH + i];
            const float4 c4 = *(const float4*)(ch + i * DH + sc);
            czT[(sc + 0) * 72 + i] = (_Float16)(c4.x * rz);
            czT[(sc + 1) * 72 + i] = (_Float16)(c4.y * rz);
            czT[(sc + 2) * 72 + i] = (_Float16)(c4.z * rz);
            czT[(sc + 3) * 72 + i] = (_Float16)(c4.w * rz);
        }
    }
    __syncthreads();

    // persistent A-frags: czT strip j = 16w + ln, k-steps 0/1
    const half8 a0 = *(const half8*)(czT + (16 * w + ln) * 72 + 0 + q8 * 8);
    const half8 a1 = *(const half8*)(czT + (16 * w + ln) * 72 + 32 + q8 * 8);

    for (int r = 0; r < 4; ++r) {
        // fp32 natural-layout staging
        #pragma unroll
        for (int p = 0; p < 4; ++p)
            *(float4*)(qf + (r0 + 16 * p) * 68 + sc) = pq[p];
        __syncthreads();
        // transpose + exp + column-sum partials
        {
            const int s  = t & 63;
            const int cg = t >> 6;          // chunk group: owns chunks cg, cg+4
            float wsum = 0.f;
            #pragma unroll
            for (int h = 0; h < 2; ++h) {
                const int cc = cg + 4 * h;
                half8 pk8;
                #pragma unroll
                for (int jj = 0; jj < 8; ++jj) {
                    const float e = __expf(qf[(8 * cc + jj) * 68 + s]);
                    wsum += e;
                    pk8[jj] = (_Float16)e;
                }
                *(half8*)(eqT + s * 64 + ((cc ^ (s & 7)) * 8)) = pk8;
            }
            wred[s * 4 + cg] = wsum;
        }
        __syncthreads();
        // prefetch next round's q while MFMA runs
        if (r < 3) {
            #pragma unroll
            for (int p = 0; p < 4; ++p)
                pq[p] = *(const float4*)(qh + (size_t)(r0 + 16 * p) * SEQ
                                         + s0 + (r + 1) * 64 + sc);
        }
        if (t < 64)
            rwsh[t] = QSCALE / (wred[t * 4] + wred[t * 4 + 1]
                                + wred[t * 4 + 2] + wred[t * 4 + 3]);
        // MFMA: 2 K-steps x 4 n-tiles
        floatx4 acc[4];
        #pragma unroll
        for (int nt = 0; nt < 4; ++nt) acc[nt] = (floatx4){0.f, 0.f, 0.f, 0.f};
        #pragma unroll
        for (int st = 0; st < 2; ++st) {
            const half8 a = (st == 0) ? a0 : a1;
            #pragma unroll
            for (int nt = 0; nt < 4; ++nt) {
                const int s  = 16 * nt + ln;
                const int cc = st * 4 + q8;
                const half8 b = *(const half8*)(eqT + s * 64 + ((cc ^ (s & 7)) * 8));
                acc[nt] = __builtin_amdgcn_mfma_f32_16x16x32_f16(a, b, acc[nt], 0, 0, 0);
            }
        }
        __syncthreads();   // rwsh visibility for epilogue
        // epilogue: scale by QSCALE/W_s, store fp32
        float* oh = out + (size_t)head * DH * SEQ + s0 + r * 64;
        #pragma unroll
        for (int nt = 0; nt < 4; ++nt) {
            const int s = 16 * nt + ln;
            const float rw = rwsh[s];
            #pragma unroll
            for (int rr = 0; rr < 4; ++rr) {
                const int j = 16 * w + q8 * 4 + rr;
                oh[(size_t)j * SEQ + s] = acc[nt][rr] * rw;
            }
        }
    }
}

extern "C" void kernel_launch(void* const* d_in, const int* in_sizes, int n_in,
                              void* d_out, int out_size, void* d_ws, size_t ws_size,
                              hipStream_t stream)
{
    const float* q = (const float*)d_in[0];
    const float* k = (const float*)d_in[1];
    const float* v = (const float*)d_in[2];
    float* out = (float*)d_out;

    float* ctx = (float*)d_ws;                 // 32*64*64 fp32 = 512 KiB
    float* Z   = ctx + BHEADS * DH * DH;       // 32*64 fp32

    const size_t zero_bytes = (size_t)(BHEADS * DH * DH + BHEADS * DH) * sizeof(float);
    hipMemsetAsync(d_ws, 0, zero_bytes, stream);

    ctx_kernel<<<dim3(32, BHEADS), 256, 0, stream>>>(k, v, ctx, Z);
    out_kernel<<<dim3(32, BHEADS), 256, 0, stream>>>(q, ctx, Z, out);
}